// Round 3
// baseline (1129.182 us; speedup 1.0000x reference)
//
#include <hip/hip_runtime.h>
#include <hip/hip_bf16.h>

#define Bx 16
#define Cx 256
#define Hx 96
#define Wx 96
#define HWx 9216
#define NTOK 147456
#define Gx 16
#define GRPN 147456.0f

typedef unsigned short u16;
typedef unsigned int u32;
typedef __attribute__((ext_vector_type(8))) short short8;
typedef __attribute__((ext_vector_type(4))) float float4_;
typedef __attribute__((ext_vector_type(4))) unsigned short us4;
typedef __attribute__((ext_vector_type(8))) unsigned short us8;
typedef __attribute__((ext_vector_type(4))) unsigned int ui4;

__device__ __forceinline__ float b2f(u16 u){ u32 x = ((u32)u)<<16; float f; __builtin_memcpy(&f,&x,4); return f; }
__device__ __forceinline__ u16 f2b(float f){ u32 x; __builtin_memcpy(&x,&f,4); x += 0x7FFFu + ((x>>16)&1u); return (u16)(x>>16); }
__device__ __forceinline__ float sigm(float v){ return 1.0f/(1.0f+__expf(-v)); }

// ---------------- transpose x[b,c,hw] (fp32) -> xT[b,hw,c] (bf16) ----------------
__global__ __launch_bounds__(256) void k_transpose(const float* __restrict__ X, u16* __restrict__ XT){
  __shared__ u16 tile[32][36];
  int blk = blockIdx.x;
  int ct  = blk & 7;
  int hwt = (blk >> 3) % 288;
  int b   = blk / 2304;
  int c0 = ct*32, hw0 = hwt*32;
  int t = threadIdx.x;
  int r  = t >> 3;            // load: c-row   | store: hw-row
  int q4 = (t & 7) << 2;      // load: hw-off  | store: c-off
  float4_ v = *(const float4_*)&X[((size_t)(b*Cx + c0 + r))*HWx + hw0 + q4];
  tile[r][q4+0]=f2b(v[0]); tile[r][q4+1]=f2b(v[1]); tile[r][q4+2]=f2b(v[2]); tile[r][q4+3]=f2b(v[3]);
  __syncthreads();
  us4 o = { tile[q4+0][r], tile[q4+1][r], tile[q4+2][r], tile[q4+3][r] };
  *(us4*)&XT[((size_t)(b*HWx + hw0 + r))*Cx + c0 + q4] = o;
}

// ---------------- GEMM: Y[n,o] = sum_c A[n,c]*Wm[o,c]  (MFMA bf16, fp32 weights) ----------------
// MODE 0: store bf16 + groupnorm stats atomics. MODE 1: gate epilogue (sigmoid(+bias), fused=0.25*S*gate in-place).
// Grid: 1-D 4608 blocks with bijective XCD-chunk swizzle: each XCD owns a contiguous n-range
// with all 4 o-tiles adjacent -> A-panel fetched ~once.
#define BM 128
#define BN 64
#define LDA 40
#define LDB 264

template<int MODE>
__global__ __launch_bounds__(256) void k_gemm(const u16* __restrict__ A,
                                              const float* __restrict__ Wm,
                                              u16* __restrict__ Y,
                                              float* __restrict__ stats,
                                              const float* __restrict__ bias,
                                              u16* __restrict__ Sb)
{
  __shared__ u16 Ws[BN*LDB];
  __shared__ u16 As[BM*LDA];
  __shared__ float red[4][16][2];
  const int tid = threadIdx.x;
  int lin = blockIdx.x;
  int swz = (lin & 7) * 576 + (lin >> 3);   // 4608/8 chunks; o fastest within chunk
  const int n0 = (swz >> 2) * BM;
  const int o0 = (swz & 3) * BN;
  // W panel (64 x 256) resident for whole K loop: fp32 -> bf16 convert on stage
  #pragma unroll
  for (int it=0; it<16; ++it){
    int cid = tid + it*256;        // 0..4095
    int row = cid >> 6;            // 0..63
    int ko  = (cid & 63) << 2;     // 0..252 step 4
    float4_ w4 = *(const float4_*)&Wm[(size_t)(o0+row)*Cx + ko];
    us4 wb = { f2b(w4[0]), f2b(w4[1]), f2b(w4[2]), f2b(w4[3]) };
    *(us4*)&Ws[row*LDB + ko] = wb;
  }
  const int lane = tid & 63;
  const int wid  = tid >> 6;
  const int lm   = lane & 15;
  const int quad = lane >> 4;
  const int wn = wid & 1;     // n offset 0/64
  const int wo = wid >> 1;    // o offset 0/32
  float4_ acc[4][2];
  #pragma unroll
  for (int i=0;i<4;++i){ acc[i][0] = (float4_)0.0f; acc[i][1] = (float4_)0.0f; }
  for (int kk=0; kk<Cx; kk+=32){
    __syncthreads();
    #pragma unroll
    for (int it=0; it<2; ++it){
      int cid = tid + it*256;
      int r = cid >> 2;
      int ko = (cid & 3) << 3;
      *(ui4*)&As[r*LDA + ko] = *(const ui4*)&A[(size_t)(n0+r)*Cx + kk + ko];
    }
    __syncthreads();
    short8 af[4], bf[2];
    #pragma unroll
    for (int i=0;i<4;++i) af[i] = *(const short8*)&As[(wn*64 + i*16 + lm)*LDA + quad*8];
    #pragma unroll
    for (int j=0;j<2;++j) bf[j] = *(const short8*)&Ws[(wo*32 + j*16 + lm)*LDB + kk + quad*8];
    #pragma unroll
    for (int i=0;i<4;++i)
      #pragma unroll
      for (int j=0;j<2;++j)
        acc[i][j] = __builtin_amdgcn_mfma_f32_16x16x32_bf16(af[i], bf[j], acc[i][j], 0, 0, 0);
  }
  const int b = n0 / HWx;
  if (MODE == 1){
    #pragma unroll
    for (int i=0;i<4;++i){
      #pragma unroll
      for (int j=0;j<2;++j){
        int oc = o0 + wo*32 + j*16 + lm;
        float bb = bias[oc];
        #pragma unroll
        for (int r=0;r<4;++r){
          int row = n0 + wn*64 + i*16 + quad*4 + r;
          size_t idx = (size_t)row*Cx + oc;
          float g = sigm(acc[i][j][r] + bb);
          Y[idx] = f2b(0.25f * b2f(Sb[idx]) * g);
        }
      }
    }
  } else {
    float s0=0,s1=0,q0=0,q1=0;
    #pragma unroll
    for (int i=0;i<4;++i){
      #pragma unroll
      for (int j=0;j<2;++j){
        int oc = o0 + wo*32 + j*16 + lm;
        #pragma unroll
        for (int r=0;r<4;++r){
          int row = n0 + wn*64 + i*16 + quad*4 + r;
          float v = acc[i][j][r];
          Y[(size_t)row*Cx + oc] = f2b(v);
          if (j==0){ s0+=v; q0+=v*v; } else { s1+=v; q1+=v*v; }
        }
      }
    }
    s0 += __shfl_xor(s0,16); s0 += __shfl_xor(s0,32);
    q0 += __shfl_xor(q0,16); q0 += __shfl_xor(q0,32);
    s1 += __shfl_xor(s1,16); s1 += __shfl_xor(s1,32);
    q1 += __shfl_xor(q1,16); q1 += __shfl_xor(q1,32);
    if (tid < 128) ((float*)red)[tid] = 0.0f;
    __syncthreads();
    if (lane < 16){
      atomicAdd(&red[wo*2+0][lm][0], s0);
      atomicAdd(&red[wo*2+0][lm][1], q0);
      atomicAdd(&red[wo*2+1][lm][0], s1);
      atomicAdd(&red[wo*2+1][lm][1], q1);
    }
    __syncthreads();
    if (tid < 4){
      float ss=0, qq=0;
      #pragma unroll
      for (int k=0;k<16;++k){ ss += red[tid][k][0]; qq += red[tid][k][1]; }
      int g = (o0 >> 4) + tid;
      atomicAdd(&stats[(b*Gx + g)*2 + 0], ss);
      atomicAdd(&stats[(b*Gx + g)*2 + 1], qq);
    }
  }
}

// ---------------- stats -> mu, rstd ----------------
__global__ void k_finalize(const float* __restrict__ st, float* __restrict__ mr){
  int i = threadIdx.x;   // 256 = 16b x 16g
  float s = st[i*2+0], q = st[i*2+1];
  float mu  = s * (1.0f/GRPN);
  float var = q * (1.0f/GRPN) - mu*mu;
  mr[i*2+0] = mu;
  mr[i*2+1] = rsqrtf(var + 1e-5f);
}

// ---------------- W-direction scans (lr + rl) -> S, fused GN1+SiLU, REGISTER-resident ----------------
// Old version: 48KB LDS -> 3 blocks/CU -> 14% occupancy -> serial scan chain latency exposed.
// Now: 96-elem row kept as 48 packed-bf16 u32 registers (ins + fwd-scan acc), zero LDS,
// __launch_bounds__(128,4) caps VGPR at 128 -> 4 waves/SIMD. Bit-identical numerics.
__global__ __launch_bounds__(128, 4) void k_scan_w(const u16* __restrict__ Y1, u16* __restrict__ Xp, u16* __restrict__ S,
    const float* __restrict__ ap, const float* __restrict__ bp, const float* __restrict__ cpr, const float* __restrict__ dp,
    const float* __restrict__ mr, const float* __restrict__ gwv, const float* __restrict__ gbv){
  int blk = blockIdx.x;
  int ch = blk & 1;
  int row = blk >> 1;
  int h = row % Hx, b = row / Hx;
  int t = threadIdx.x;
  int c = ch*128 + t;
  float A0 = sigm(ap[c]),      B0 = bp[c],      C0 = cpr[c],      D0 = dp[c];
  float A1 = sigm(ap[Cx+c]),   B1 = bp[Cx+c],   C1 = cpr[Cx+c],   D1 = dp[Cx+c];
  int g = c >> 4;
  float mu = mr[(b*Gx+g)*2], rs = mr[(b*Gx+g)*2+1];
  float gwc = gwv[c], gbc = gbv[c];
  const u16* base = Y1 + ((size_t)(b*Hx + h)*Wx)*Cx + c;
  u16* xpb = Xp + ((size_t)(b*Hx + h)*Wx)*Cx + c;
  u32 ins[48];
  u32 acc[48];
  // load + GN1 + SiLU; store normed to xp; keep packed in regs
  #pragma unroll
  for (int w=0; w<Wx; w+=2){
    float x0 = (b2f(base[(size_t)w*Cx])     - mu)*rs*gwc + gbc;
    float x1 = (b2f(base[(size_t)(w+1)*Cx]) - mu)*rs*gwc + gbc;
    u16 v0 = f2b(x0 * sigm(x0));
    u16 v1 = f2b(x1 * sigm(x1));
    xpb[(size_t)w*Cx]     = v0;
    xpb[(size_t)(w+1)*Cx] = v1;
    ins[w>>1] = (u32)v0 | ((u32)v1 << 16);
  }
  // forward scan -> acc (packed bf16, same rounding as old LDS version)
  float hs = 0.0f;
  #pragma unroll
  for (int w=0; w<Wx; ++w){
    u32 pk = ins[w>>1];
    float xv = b2f((u16)((w&1) ? (pk>>16) : (pk&0xffffu)));
    hs = A0*hs + B0*xv;
    u16 ob = f2b(C0*hs + D0*xv);
    if (w&1) acc[w>>1] |= ((u32)ob << 16); else acc[w>>1] = (u32)ob;
  }
  // backward scan + combine -> S
  hs = 0.0f;
  u16* sb = S + ((size_t)(b*Hx + h)*Wx)*Cx + c;
  #pragma unroll
  for (int w=Wx-1; w>=0; --w){
    u32 pk = ins[w>>1];
    float xv = b2f((u16)((w&1) ? (pk>>16) : (pk&0xffffu)));
    hs = A1*hs + B1*xv;
    u32 ak = acc[w>>1];
    float av = b2f((u16)((w&1) ? (ak>>16) : (ak&0xffffu)));
    sb[(size_t)w*Cx] = f2b(C1*hs + D1*xv + av);
  }
}

// ---------------- H-direction scans (tb + bt), accumulate into S, REGISTER-resident ----------------
__global__ __launch_bounds__(128, 4) void k_scan_h(const u16* __restrict__ Xp, u16* __restrict__ S,
    const float* __restrict__ ap, const float* __restrict__ bp, const float* __restrict__ cpr, const float* __restrict__ dp){
  int blk = blockIdx.x;
  int ch = blk & 1;
  int col = blk >> 1;
  int w = col % Wx, b = col / Wx;
  int t = threadIdx.x;
  int c = ch*128 + t;
  float A2 = sigm(ap[2*Cx+c]), B2 = bp[2*Cx+c], C2 = cpr[2*Cx+c], D2 = dp[2*Cx+c];
  float A3 = sigm(ap[3*Cx+c]), B3 = bp[3*Cx+c], C3 = cpr[3*Cx+c], D3 = dp[3*Cx+c];
  const u16* base = Xp + ((size_t)(b*Hx)*Wx + w)*Cx + c;
  u32 ins[48];
  u32 acc[48];
  #pragma unroll
  for (int h=0; h<Hx; h+=2){
    u16 v0 = base[(size_t)h*Wx*Cx];
    u16 v1 = base[(size_t)(h+1)*Wx*Cx];
    ins[h>>1] = (u32)v0 | ((u32)v1 << 16);
  }
  float hs = 0.0f;
  #pragma unroll
  for (int h=0; h<Hx; ++h){
    u32 pk = ins[h>>1];
    float xv = b2f((u16)((h&1) ? (pk>>16) : (pk&0xffffu)));
    hs = A2*hs + B2*xv;
    u16 ob = f2b(C2*hs + D2*xv);
    if (h&1) acc[h>>1] |= ((u32)ob << 16); else acc[h>>1] = (u32)ob;
  }
  hs = 0.0f;
  u16* sb = S + ((size_t)(b*Hx)*Wx + w)*Cx + c;
  #pragma unroll
  for (int h=Hx-1; h>=0; --h){
    u32 pk = ins[h>>1];
    float xv = b2f((u16)((h&1) ? (pk>>16) : (pk&0xffffu)));
    hs = A3*hs + B3*xv;
    u32 ak = acc[h>>1];
    float av = b2f((u16)((h&1) ? (ak>>16) : (ak&0xffffu)));
    size_t off = (size_t)h*Wx*Cx;
    sb[off] = f2b(C3*hs + D3*xv + av + b2f(sb[off]));
  }
}

// ---------------- depthwise 3x3, channels-last (bf16 act, fp32 weights) ----------------
// Weights in registers; 4 w-outputs x 4 channels per thread; input patch reused across outputs.
__global__ __launch_bounds__(256) void k_dwconv(const u16* __restrict__ F, const float* __restrict__ dwW, u16* __restrict__ O){
  __shared__ float wl[2304];
  int t = threadIdx.x;
  #pragma unroll
  for (int i=0;i<9;++i) wl[t + i*256] = dwW[t + i*256];
  __syncthreads();
  int blk = blockIdx.x;
  int w16 = blk % (Wx/16);
  int h   = (blk/(Wx/16)) % Hx;
  int b   = blk / ((Wx/16)*Hx);
  int cq = (t & 63) << 2;            // channel quad base (lane-major -> 512B coalesced)
  int w0 = (w16 << 4) + ((t >> 6) << 2);  // 4 outputs per thread, wave-uniform
  float wt[36];
  #pragma unroll
  for (int j=0;j<9;++j) *(float4_*)&wt[4*j] = *(const float4_*)&wl[cq*9 + 4*j];
  float acc[4][4];
  #pragma unroll
  for (int ow=0;ow<4;++ow){ acc[ow][0]=0.0f; acc[ow][1]=0.0f; acc[ow][2]=0.0f; acc[ow][3]=0.0f; }
  const u16* Fb = F + ((size_t)(b*Hx)*Wx)*Cx + cq;
  #pragma unroll
  for (int ky=0; ky<3; ++ky){
    int hh = h + ky - 1;
    if (hh < 0 || hh >= Hx) continue;
    #pragma unroll
    for (int j=0; j<6; ++j){            // input cols w0-1 .. w0+4
      int ww = w0 + j - 1;
      if (ww < 0 || ww >= Wx) continue;
      us4 v = *(const us4*)&Fb[((size_t)hh*Wx + ww)*Cx];
      float f0=b2f(v[0]), f1=b2f(v[1]), f2=b2f(v[2]), f3=b2f(v[3]);
      #pragma unroll
      for (int ow = (j-2<0?0:j-2); ow <= (j<3?j:3); ++ow){
        int kidx = ky*3 + (j - ow);
        acc[ow][0] += f0 * wt[0*9 + kidx];
        acc[ow][1] += f1 * wt[1*9 + kidx];
        acc[ow][2] += f2 * wt[2*9 + kidx];
        acc[ow][3] += f3 * wt[3*9 + kidx];
      }
    }
  }
  #pragma unroll
  for (int ow=0; ow<4; ++ow){
    us4 o = { f2b(acc[ow][0]), f2b(acc[ow][1]), f2b(acc[ow][2]), f2b(acc[ow][3]) };
    *(us4*)&O[((size_t)((b*Hx+h)*Wx) + w0 + ow)*Cx + cq] = o;
  }
}

// ---------------- GN-apply + SiLU + transpose back to [b,c,hw] (fp32 out) ----------------
__global__ __launch_bounds__(256) void k_norm_tr(const u16* __restrict__ Y3, float* __restrict__ Out,
    const float* __restrict__ mr, const float* __restrict__ gw, const float* __restrict__ gb){
  __shared__ float tile[32][36];   // [hw][c]
  int blk = blockIdx.x;
  int ct  = blk & 7;
  int hwt = (blk >> 3) % 288;
  int b   = blk / 2304;
  int c0 = ct*32, hw0 = hwt*32;
  int t = threadIdx.x;
  int r  = t >> 3;
  int q4 = (t & 7) << 2;
  us4 v = *(const us4*)&Y3[((size_t)(b*HWx + hw0 + r))*Cx + c0 + q4];
  int g = (c0 + q4) >> 4;
  float mu = mr[(b*Gx+g)*2], rs = mr[(b*Gx+g)*2+1];
  #pragma unroll
  for (int i=0;i<4;++i){
    float xn = (b2f(v[i]) - mu)*rs*gw[c0+q4+i] + gb[c0+q4+i];
    tile[r][q4+i] = xn * sigm(xn);
  }
  __syncthreads();
  float4_ o = { tile[q4+0][r], tile[q4+1][r], tile[q4+2][r], tile[q4+3][r] };
  *(float4_*)&Out[((size_t)(b*Cx + c0 + r))*HWx + hw0 + q4] = o;
}

extern "C" void kernel_launch(void* const* d_in, const int* in_sizes, int n_in,
                              void* d_out, int out_size, void* d_ws, size_t ws_size,
                              hipStream_t stream){
  (void)in_sizes; (void)n_in; (void)out_size; (void)ws_size;
  const float* x    = (const float*)d_in[0];
  const float* in_w = (const float*)d_in[1];
  const float* gn1w = (const float*)d_in[2];
  const float* gn1b = (const float*)d_in[3];
  const float* ap   = (const float*)d_in[4];
  const float* bp   = (const float*)d_in[5];
  const float* cp   = (const float*)d_in[6];
  const float* dp   = (const float*)d_in[7];
  const float* gw   = (const float*)d_in[8];
  const float* gb   = (const float*)d_in[9];
  const float* dww  = (const float*)d_in[10];
  const float* pww  = (const float*)d_in[11];
  const float* gn2w = (const float*)d_in[12];
  const float* gn2b = (const float*)d_in[13];
  float* out = (float*)d_out;
  char* ws = (char*)d_ws;
  const size_t NB = (size_t)NTOK * Cx * 2;   // 75,497,472 bytes per bf16 tensor
  u16* xT = (u16*)(ws);            // also reused for dwconv output
  u16* y1 = (u16*)(ws + NB);       // also reused for GEMM3 output
  u16* xp = (u16*)(ws + 2*NB);
  u16* S  = (u16*)(ws + 3*NB);     // scan sum -> fused (in-place)
  float* stats1 = (float*)(ws + 4*NB);
  float* stats2 = stats1 + 512;
  float* mr1    = stats1 + 1024;
  float* mr2    = stats1 + 1536;

  hipMemsetAsync(stats1, 0, 1024*sizeof(float), stream);

  k_transpose<<<36864, 256, 0, stream>>>(x, xT);
  k_gemm<0><<<4608, 256, 0, stream>>>(xT, in_w, y1, stats1, nullptr, nullptr);
  k_finalize<<<1, 256, 0, stream>>>(stats1, mr1);
  k_scan_w<<<Bx*Hx*2, 128, 0, stream>>>(y1, xp, S, ap, bp, cp, dp, mr1, gn1w, gn1b);
  k_scan_h<<<Bx*Wx*2, 128, 0, stream>>>(xp, S, ap, bp, cp, dp);
  k_gemm<1><<<4608, 256, 0, stream>>>(xp, gw, S, nullptr, gb, S);
  k_dwconv<<<Bx*Hx*(Wx/16), 256, 0, stream>>>(S, dww, xT);
  k_gemm<0><<<4608, 256, 0, stream>>>(xT, pww, y1, stats2, nullptr, nullptr);
  k_finalize<<<1, 256, 0, stream>>>(stats2, mr2);
  k_norm_tr<<<36864, 256, 0, stream>>>(y1, out, mr2, gn2w, gn2b);
}

// Round 4
// 841.839 us; speedup vs baseline: 1.3413x; 1.3413x over previous
//
#include <hip/hip_runtime.h>
#include <hip/hip_bf16.h>

#define Bx 16
#define Cx 256
#define Hx 96
#define Wx 96
#define HWx 9216
#define NTOK 147456
#define Gx 16
#define GRPN 147456.0f

typedef unsigned short u16;
typedef unsigned int u32;
typedef __attribute__((ext_vector_type(8))) short short8;
typedef __attribute__((ext_vector_type(4))) float float4_;
typedef __attribute__((ext_vector_type(4))) unsigned short us4;
typedef __attribute__((ext_vector_type(8))) unsigned short us8;
typedef __attribute__((ext_vector_type(4))) unsigned int ui4;

__device__ __forceinline__ float b2f(u16 u){ u32 x = ((u32)u)<<16; float f; __builtin_memcpy(&f,&x,4); return f; }
__device__ __forceinline__ u16 f2b(float f){ u32 x; __builtin_memcpy(&x,&f,4); x += 0x7FFFu + ((x>>16)&1u); return (u16)(x>>16); }
__device__ __forceinline__ float sigm(float v){ return 1.0f/(1.0f+__expf(-v)); }

// ---------------- transpose x[b,c,hw] (fp32) -> xT[b,hw,c] (bf16) ----------------
__global__ __launch_bounds__(256) void k_transpose(const float* __restrict__ X, u16* __restrict__ XT){
  __shared__ u16 tile[32][36];
  int blk = blockIdx.x;
  int ct  = blk & 7;
  int hwt = (blk >> 3) % 288;
  int b   = blk / 2304;
  int c0 = ct*32, hw0 = hwt*32;
  int t = threadIdx.x;
  int r  = t >> 3;            // load: c-row   | store: hw-row
  int q4 = (t & 7) << 2;      // load: hw-off  | store: c-off
  float4_ v = *(const float4_*)&X[((size_t)(b*Cx + c0 + r))*HWx + hw0 + q4];
  tile[r][q4+0]=f2b(v[0]); tile[r][q4+1]=f2b(v[1]); tile[r][q4+2]=f2b(v[2]); tile[r][q4+3]=f2b(v[3]);
  __syncthreads();
  us4 o = { tile[q4+0][r], tile[q4+1][r], tile[q4+2][r], tile[q4+3][r] };
  *(us4*)&XT[((size_t)(b*HWx + hw0 + r))*Cx + c0 + q4] = o;
}

// ---------------- GEMM: Y[n,o] = sum_c A[n,c]*Wm[o,c]  (MFMA bf16, fp32 weights) ----------------
// MODE 0: store bf16 + groupnorm stats atomics. MODE 1: gate epilogue (sigmoid(+bias), fused=0.25*S*gate in-place).
// Grid: 1-D 4608 blocks with bijective XCD-chunk swizzle: each XCD owns a contiguous n-range
// with all 4 o-tiles adjacent -> A-panel fetched ~once.
#define BM 128
#define BN 64
#define LDA 40
#define LDB 264

template<int MODE>
__global__ __launch_bounds__(256) void k_gemm(const u16* __restrict__ A,
                                              const float* __restrict__ Wm,
                                              u16* __restrict__ Y,
                                              float* __restrict__ stats,
                                              const float* __restrict__ bias,
                                              u16* __restrict__ Sb)
{
  __shared__ u16 Ws[BN*LDB];
  __shared__ u16 As[BM*LDA];
  __shared__ float red[4][16][2];
  const int tid = threadIdx.x;
  int lin = blockIdx.x;
  int swz = (lin & 7) * 576 + (lin >> 3);   // 4608/8 chunks; o fastest within chunk
  const int n0 = (swz >> 2) * BM;
  const int o0 = (swz & 3) * BN;
  // W panel (64 x 256) resident for whole K loop: fp32 -> bf16 convert on stage
  #pragma unroll
  for (int it=0; it<16; ++it){
    int cid = tid + it*256;        // 0..4095
    int row = cid >> 6;            // 0..63
    int ko  = (cid & 63) << 2;     // 0..252 step 4
    float4_ w4 = *(const float4_*)&Wm[(size_t)(o0+row)*Cx + ko];
    us4 wb = { f2b(w4[0]), f2b(w4[1]), f2b(w4[2]), f2b(w4[3]) };
    *(us4*)&Ws[row*LDB + ko] = wb;
  }
  const int lane = tid & 63;
  const int wid  = tid >> 6;
  const int lm   = lane & 15;
  const int quad = lane >> 4;
  const int wn = wid & 1;     // n offset 0/64
  const int wo = wid >> 1;    // o offset 0/32
  float4_ acc[4][2];
  #pragma unroll
  for (int i=0;i<4;++i){ acc[i][0] = (float4_)0.0f; acc[i][1] = (float4_)0.0f; }
  for (int kk=0; kk<Cx; kk+=32){
    __syncthreads();
    #pragma unroll
    for (int it=0; it<2; ++it){
      int cid = tid + it*256;
      int r = cid >> 2;
      int ko = (cid & 3) << 3;
      *(ui4*)&As[r*LDA + ko] = *(const ui4*)&A[(size_t)(n0+r)*Cx + kk + ko];
    }
    __syncthreads();
    short8 af[4], bf[2];
    #pragma unroll
    for (int i=0;i<4;++i) af[i] = *(const short8*)&As[(wn*64 + i*16 + lm)*LDA + quad*8];
    #pragma unroll
    for (int j=0;j<2;++j) bf[j] = *(const short8*)&Ws[(wo*32 + j*16 + lm)*LDB + kk + quad*8];
    #pragma unroll
    for (int i=0;i<4;++i)
      #pragma unroll
      for (int j=0;j<2;++j)
        acc[i][j] = __builtin_amdgcn_mfma_f32_16x16x32_bf16(af[i], bf[j], acc[i][j], 0, 0, 0);
  }
  const int b = n0 / HWx;
  if (MODE == 1){
    #pragma unroll
    for (int i=0;i<4;++i){
      #pragma unroll
      for (int j=0;j<2;++j){
        int oc = o0 + wo*32 + j*16 + lm;
        float bb = bias[oc];
        #pragma unroll
        for (int r=0;r<4;++r){
          int row = n0 + wn*64 + i*16 + quad*4 + r;
          size_t idx = (size_t)row*Cx + oc;
          float g = sigm(acc[i][j][r] + bb);
          Y[idx] = f2b(0.25f * b2f(Sb[idx]) * g);
        }
      }
    }
  } else {
    float s0=0,s1=0,q0=0,q1=0;
    #pragma unroll
    for (int i=0;i<4;++i){
      #pragma unroll
      for (int j=0;j<2;++j){
        int oc = o0 + wo*32 + j*16 + lm;
        #pragma unroll
        for (int r=0;r<4;++r){
          int row = n0 + wn*64 + i*16 + quad*4 + r;
          float v = acc[i][j][r];
          Y[(size_t)row*Cx + oc] = f2b(v);
          if (j==0){ s0+=v; q0+=v*v; } else { s1+=v; q1+=v*v; }
        }
      }
    }
    s0 += __shfl_xor(s0,16); s0 += __shfl_xor(s0,32);
    q0 += __shfl_xor(q0,16); q0 += __shfl_xor(q0,32);
    s1 += __shfl_xor(s1,16); s1 += __shfl_xor(s1,32);
    q1 += __shfl_xor(q1,16); q1 += __shfl_xor(q1,32);
    if (tid < 128) ((float*)red)[tid] = 0.0f;
    __syncthreads();
    if (lane < 16){
      atomicAdd(&red[wo*2+0][lm][0], s0);
      atomicAdd(&red[wo*2+0][lm][1], q0);
      atomicAdd(&red[wo*2+1][lm][0], s1);
      atomicAdd(&red[wo*2+1][lm][1], q1);
    }
    __syncthreads();
    if (tid < 4){
      float ss=0, qq=0;
      #pragma unroll
      for (int k=0;k<16;++k){ ss += red[tid][k][0]; qq += red[tid][k][1]; }
      int g = (o0 >> 4) + tid;
      atomicAdd(&stats[(b*Gx + g)*2 + 0], ss);
      atomicAdd(&stats[(b*Gx + g)*2 + 1], qq);
    }
  }
}

// ---------------- stats -> mu, rstd ----------------
__global__ void k_finalize(const float* __restrict__ st, float* __restrict__ mr){
  int i = threadIdx.x;   // 256 = 16b x 16g
  float s = st[i*2+0], q = st[i*2+1];
  float mu  = s * (1.0f/GRPN);
  float var = q * (1.0f/GRPN) - mu*mu;
  mr[i*2+0] = mu;
  mr[i*2+1] = rsqrtf(var + 1e-5f);
}

// ---------------- W-direction scans (lr + rl) -> S, fused GN1+SiLU ----------------
// Hybrid: ins staged in LDS (24 KB -> 6 blocks/CU, 2x round-2 occupancy); forward-scan
// partials packed bf16 in 48 u32 REGISTERS (half the reg demand of the spilled round-3
// version; plain __launch_bounds__(128) leaves the 256-VGPR cap -> no spill).
// Each thread only touches its own LDS column -> no barriers. Bit-identical numerics.
__global__ __launch_bounds__(128) void k_scan_w(const u16* __restrict__ Y1, u16* __restrict__ Xp, u16* __restrict__ S,
    const float* __restrict__ ap, const float* __restrict__ bp, const float* __restrict__ cpr, const float* __restrict__ dp,
    const float* __restrict__ mr, const float* __restrict__ gwv, const float* __restrict__ gbv){
  __shared__ u16 ins[96*128];
  int blk = blockIdx.x;
  int ch = blk & 1;
  int row = blk >> 1;
  int h = row % Hx, b = row / Hx;
  int t = threadIdx.x;
  int c = ch*128 + t;
  float A0 = sigm(ap[c]),      B0 = bp[c],      C0 = cpr[c],      D0 = dp[c];
  float A1 = sigm(ap[Cx+c]),   B1 = bp[Cx+c],   C1 = cpr[Cx+c],   D1 = dp[Cx+c];
  int g = c >> 4;
  float mu = mr[(b*Gx+g)*2], rs = mr[(b*Gx+g)*2+1];
  float gwc = gwv[c], gbc = gbv[c];
  const u16* base = Y1 + ((size_t)(b*Hx + h)*Wx)*Cx + c;
  u16* xpb = Xp + ((size_t)(b*Hx + h)*Wx)*Cx + c;
  for (int w=0; w<Wx; ++w){
    float xn = (b2f(base[(size_t)w*Cx]) - mu)*rs*gwc + gbc;
    u16 v = f2b(xn * sigm(xn));
    ins[w*128+t] = v;
    xpb[(size_t)w*Cx] = v;
  }
  u32 acc[48];
  float hs = 0.0f;
  #pragma unroll
  for (int w2=0; w2<48; ++w2){
    float x0 = b2f(ins[(2*w2)*128+t]);
    hs = A0*hs + B0*x0;
    u16 o0 = f2b(C0*hs + D0*x0);
    float x1 = b2f(ins[(2*w2+1)*128+t]);
    hs = A0*hs + B0*x1;
    u16 o1 = f2b(C0*hs + D0*x1);
    acc[w2] = (u32)o0 | ((u32)o1 << 16);
  }
  hs = 0.0f;
  u16* sb = S + ((size_t)(b*Hx + h)*Wx)*Cx + c;
  #pragma unroll
  for (int w2=47; w2>=0; --w2){
    u32 ak = acc[w2];
    float x1 = b2f(ins[(2*w2+1)*128+t]);
    hs = A1*hs + B1*x1;
    sb[(size_t)(2*w2+1)*Cx] = f2b(C1*hs + D1*x1 + b2f((u16)(ak>>16)));
    float x0 = b2f(ins[(2*w2)*128+t]);
    hs = A1*hs + B1*x0;
    sb[(size_t)(2*w2)*Cx] = f2b(C1*hs + D1*x0 + b2f((u16)(ak&0xffffu)));
  }
}

// ---------------- H-direction scans (tb + bt), accumulate into S ----------------
__global__ __launch_bounds__(128) void k_scan_h(const u16* __restrict__ Xp, u16* __restrict__ S,
    const float* __restrict__ ap, const float* __restrict__ bp, const float* __restrict__ cpr, const float* __restrict__ dp){
  __shared__ u16 ins[96*128];
  int blk = blockIdx.x;
  int ch = blk & 1;
  int col = blk >> 1;
  int w = col % Wx, b = col / Wx;
  int t = threadIdx.x;
  int c = ch*128 + t;
  float A2 = sigm(ap[2*Cx+c]), B2 = bp[2*Cx+c], C2 = cpr[2*Cx+c], D2 = dp[2*Cx+c];
  float A3 = sigm(ap[3*Cx+c]), B3 = bp[3*Cx+c], C3 = cpr[3*Cx+c], D3 = dp[3*Cx+c];
  const u16* base = Xp + ((size_t)(b*Hx)*Wx + w)*Cx + c;
  for (int h=0; h<Hx; ++h) ins[h*128+t] = base[(size_t)h*Wx*Cx];
  u32 acc[48];
  float hs = 0.0f;
  #pragma unroll
  for (int h2=0; h2<48; ++h2){
    float x0 = b2f(ins[(2*h2)*128+t]);
    hs = A2*hs + B2*x0;
    u16 o0 = f2b(C2*hs + D2*x0);
    float x1 = b2f(ins[(2*h2+1)*128+t]);
    hs = A2*hs + B2*x1;
    u16 o1 = f2b(C2*hs + D2*x1);
    acc[h2] = (u32)o0 | ((u32)o1 << 16);
  }
  hs = 0.0f;
  u16* sb = S + ((size_t)(b*Hx)*Wx + w)*Cx + c;
  #pragma unroll
  for (int h2=47; h2>=0; --h2){
    u32 ak = acc[h2];
    float x1 = b2f(ins[(2*h2+1)*128+t]);
    hs = A3*hs + B3*x1;
    size_t off1 = (size_t)(2*h2+1)*Wx*Cx;
    sb[off1] = f2b(C3*hs + D3*x1 + b2f((u16)(ak>>16)) + b2f(sb[off1]));
    float x0 = b2f(ins[(2*h2)*128+t]);
    hs = A3*hs + B3*x0;
    size_t off0 = (size_t)(2*h2)*Wx*Cx;
    sb[off0] = f2b(C3*hs + D3*x0 + b2f((u16)(ak&0xffffu)) + b2f(sb[off0]));
  }
}

// ---------------- depthwise 3x3, channels-last (bf16 act, fp32 weights) ----------------
// Weights in registers; 4 w-outputs x 4 channels per thread; input patch reused across outputs.
__global__ __launch_bounds__(256) void k_dwconv(const u16* __restrict__ F, const float* __restrict__ dwW, u16* __restrict__ O){
  __shared__ float wl[2304];
  int t = threadIdx.x;
  #pragma unroll
  for (int i=0;i<9;++i) wl[t + i*256] = dwW[t + i*256];
  __syncthreads();
  int blk = blockIdx.x;
  int w16 = blk % (Wx/16);
  int h   = (blk/(Wx/16)) % Hx;
  int b   = blk / ((Wx/16)*Hx);
  int cq = (t & 63) << 2;            // channel quad base (lane-major -> 512B coalesced)
  int w0 = (w16 << 4) + ((t >> 6) << 2);  // 4 outputs per thread, wave-uniform
  float wt[36];
  #pragma unroll
  for (int j=0;j<9;++j) *(float4_*)&wt[4*j] = *(const float4_*)&wl[cq*9 + 4*j];
  float acc[4][4];
  #pragma unroll
  for (int ow=0;ow<4;++ow){ acc[ow][0]=0.0f; acc[ow][1]=0.0f; acc[ow][2]=0.0f; acc[ow][3]=0.0f; }
  const u16* Fb = F + ((size_t)(b*Hx)*Wx)*Cx + cq;
  #pragma unroll
  for (int ky=0; ky<3; ++ky){
    int hh = h + ky - 1;
    if (hh < 0 || hh >= Hx) continue;
    #pragma unroll
    for (int j=0; j<6; ++j){            // input cols w0-1 .. w0+4
      int ww = w0 + j - 1;
      if (ww < 0 || ww >= Wx) continue;
      us4 v = *(const us4*)&Fb[((size_t)hh*Wx + ww)*Cx];
      float f0=b2f(v[0]), f1=b2f(v[1]), f2=b2f(v[2]), f3=b2f(v[3]);
      #pragma unroll
      for (int ow = (j-2<0?0:j-2); ow <= (j<3?j:3); ++ow){
        int kidx = ky*3 + (j - ow);
        acc[ow][0] += f0 * wt[0*9 + kidx];
        acc[ow][1] += f1 * wt[1*9 + kidx];
        acc[ow][2] += f2 * wt[2*9 + kidx];
        acc[ow][3] += f3 * wt[3*9 + kidx];
      }
    }
  }
  #pragma unroll
  for (int ow=0; ow<4; ++ow){
    us4 o = { f2b(acc[ow][0]), f2b(acc[ow][1]), f2b(acc[ow][2]), f2b(acc[ow][3]) };
    *(us4*)&O[((size_t)((b*Hx+h)*Wx) + w0 + ow)*Cx + cq] = o;
  }
}

// ---------------- GN-apply + SiLU + transpose back to [b,c,hw] (fp32 out) ----------------
__global__ __launch_bounds__(256) void k_norm_tr(const u16* __restrict__ Y3, float* __restrict__ Out,
    const float* __restrict__ mr, const float* __restrict__ gw, const float* __restrict__ gb){
  __shared__ float tile[32][36];   // [hw][c]
  int blk = blockIdx.x;
  int ct  = blk & 7;
  int hwt = (blk >> 3) % 288;
  int b   = blk / 2304;
  int c0 = ct*32, hw0 = hwt*32;
  int t = threadIdx.x;
  int r  = t >> 3;
  int q4 = (t & 7) << 2;
  us4 v = *(const us4*)&Y3[((size_t)(b*HWx + hw0 + r))*Cx + c0 + q4];
  int g = (c0 + q4) >> 4;
  float mu = mr[(b*Gx+g)*2], rs = mr[(b*Gx+g)*2+1];
  #pragma unroll
  for (int i=0;i<4;++i){
    float xn = (b2f(v[i]) - mu)*rs*gw[c0+q4+i] + gb[c0+q4+i];
    tile[r][q4+i] = xn * sigm(xn);
  }
  __syncthreads();
  float4_ o = { tile[q4+0][r], tile[q4+1][r], tile[q4+2][r], tile[q4+3][r] };
  *(float4_*)&Out[((size_t)(b*Cx + c0 + r))*HWx + hw0 + q4] = o;
}

extern "C" void kernel_launch(void* const* d_in, const int* in_sizes, int n_in,
                              void* d_out, int out_size, void* d_ws, size_t ws_size,
                              hipStream_t stream){
  (void)in_sizes; (void)n_in; (void)out_size; (void)ws_size;
  const float* x    = (const float*)d_in[0];
  const float* in_w = (const float*)d_in[1];
  const float* gn1w = (const float*)d_in[2];
  const float* gn1b = (const float*)d_in[3];
  const float* ap   = (const float*)d_in[4];
  const float* bp   = (const float*)d_in[5];
  const float* cp   = (const float*)d_in[6];
  const float* dp   = (const float*)d_in[7];
  const float* gw   = (const float*)d_in[8];
  const float* gb   = (const float*)d_in[9];
  const float* dww  = (const float*)d_in[10];
  const float* pww  = (const float*)d_in[11];
  const float* gn2w = (const float*)d_in[12];
  const float* gn2b = (const float*)d_in[13];
  float* out = (float*)d_out;
  char* ws = (char*)d_ws;
  const size_t NB = (size_t)NTOK * Cx * 2;   // 75,497,472 bytes per bf16 tensor
  u16* xT = (u16*)(ws);            // also reused for dwconv output
  u16* y1 = (u16*)(ws + NB);       // also reused for GEMM3 output
  u16* xp = (u16*)(ws + 2*NB);
  u16* S  = (u16*)(ws + 3*NB);     // scan sum -> fused (in-place)
  float* stats1 = (float*)(ws + 4*NB);
  float* stats2 = stats1 + 512;
  float* mr1    = stats1 + 1024;
  float* mr2    = stats1 + 1536;

  hipMemsetAsync(stats1, 0, 1024*sizeof(float), stream);

  k_transpose<<<36864, 256, 0, stream>>>(x, xT);
  k_gemm<0><<<4608, 256, 0, stream>>>(xT, in_w, y1, stats1, nullptr, nullptr);
  k_finalize<<<1, 256, 0, stream>>>(stats1, mr1);
  k_scan_w<<<Bx*Hx*2, 128, 0, stream>>>(y1, xp, S, ap, bp, cp, dp, mr1, gn1w, gn1b);
  k_scan_h<<<Bx*Wx*2, 128, 0, stream>>>(xp, S, ap, bp, cp, dp);
  k_gemm<1><<<4608, 256, 0, stream>>>(xp, gw, S, nullptr, gb, S);
  k_dwconv<<<Bx*Hx*(Wx/16), 256, 0, stream>>>(S, dww, xT);
  k_gemm<0><<<4608, 256, 0, stream>>>(xT, pww, y1, stats2, nullptr, nullptr);
  k_finalize<<<1, 256, 0, stream>>>(stats2, mr2);
  k_norm_tr<<<36864, 256, 0, stream>>>(y1, out, mr2, gn2w, gn2b);
}

// Round 5
// 747.420 us; speedup vs baseline: 1.5108x; 1.1263x over previous
//
#include <hip/hip_runtime.h>
#include <hip/hip_bf16.h>

#define Bx 16
#define Cx 256
#define Hx 96
#define Wx 96
#define HWx 9216
#define NTOK 147456
#define Gx 16
#define GRPN 147456.0f

typedef unsigned short u16;
typedef unsigned int u32;
typedef __attribute__((ext_vector_type(8))) short short8;
typedef __attribute__((ext_vector_type(4))) float float4_;
typedef __attribute__((ext_vector_type(4))) unsigned short us4;
typedef __attribute__((ext_vector_type(8))) unsigned short us8;
typedef __attribute__((ext_vector_type(4))) unsigned int ui4;

__device__ __forceinline__ float b2f(u16 u){ u32 x = ((u32)u)<<16; float f; __builtin_memcpy(&f,&x,4); return f; }
__device__ __forceinline__ u16 f2b(float f){ u32 x; __builtin_memcpy(&x,&f,4); x += 0x7FFFu + ((x>>16)&1u); return (u16)(x>>16); }
__device__ __forceinline__ float sigm(float v){ return 1.0f/(1.0f+__expf(-v)); }

// ---------------- transpose x[b,c,hw] (fp32) -> xT[b,hw,c] (bf16) ----------------
__global__ __launch_bounds__(256) void k_transpose(const float* __restrict__ X, u16* __restrict__ XT){
  __shared__ u16 tile[32][36];
  int blk = blockIdx.x;
  int ct  = blk & 7;
  int hwt = (blk >> 3) % 288;
  int b   = blk / 2304;
  int c0 = ct*32, hw0 = hwt*32;
  int t = threadIdx.x;
  int r  = t >> 3;            // load: c-row   | store: hw-row
  int q4 = (t & 7) << 2;      // load: hw-off  | store: c-off
  float4_ v = *(const float4_*)&X[((size_t)(b*Cx + c0 + r))*HWx + hw0 + q4];
  tile[r][q4+0]=f2b(v[0]); tile[r][q4+1]=f2b(v[1]); tile[r][q4+2]=f2b(v[2]); tile[r][q4+3]=f2b(v[3]);
  __syncthreads();
  us4 o = { tile[q4+0][r], tile[q4+1][r], tile[q4+2][r], tile[q4+3][r] };
  *(us4*)&XT[((size_t)(b*HWx + hw0 + r))*Cx + c0 + q4] = o;
}

// ---------------- GEMM: Y[n,o] = sum_c A[n,c]*Wm[o,c]  (MFMA bf16, fp32 weights) ----------------
// MODE 0: store bf16 + groupnorm stats atomics. MODE 1: gate epilogue (sigmoid(+bias), fused=0.25*S*gate in-place).
// Grid: 1-D 4608 blocks with bijective XCD-chunk swizzle: each XCD owns a contiguous n-range
// with all 4 o-tiles adjacent -> A-panel fetched ~once.
#define BM 128
#define BN 64
#define LDA 40
#define LDB 264

template<int MODE>
__global__ __launch_bounds__(256) void k_gemm(const u16* __restrict__ A,
                                              const float* __restrict__ Wm,
                                              u16* __restrict__ Y,
                                              float* __restrict__ stats,
                                              const float* __restrict__ bias,
                                              u16* __restrict__ Sb)
{
  __shared__ u16 Ws[BN*LDB];
  __shared__ u16 As[BM*LDA];
  __shared__ float red[4][16][2];
  const int tid = threadIdx.x;
  int lin = blockIdx.x;
  int swz = (lin & 7) * 576 + (lin >> 3);   // 4608/8 chunks; o fastest within chunk
  const int n0 = (swz >> 2) * BM;
  const int o0 = (swz & 3) * BN;
  // W panel (64 x 256) resident for whole K loop: fp32 -> bf16 convert on stage
  #pragma unroll
  for (int it=0; it<16; ++it){
    int cid = tid + it*256;        // 0..4095
    int row = cid >> 6;            // 0..63
    int ko  = (cid & 63) << 2;     // 0..252 step 4
    float4_ w4 = *(const float4_*)&Wm[(size_t)(o0+row)*Cx + ko];
    us4 wb = { f2b(w4[0]), f2b(w4[1]), f2b(w4[2]), f2b(w4[3]) };
    *(us4*)&Ws[row*LDB + ko] = wb;
  }
  const int lane = tid & 63;
  const int wid  = tid >> 6;
  const int lm   = lane & 15;
  const int quad = lane >> 4;
  const int wn = wid & 1;     // n offset 0/64
  const int wo = wid >> 1;    // o offset 0/32
  float4_ acc[4][2];
  #pragma unroll
  for (int i=0;i<4;++i){ acc[i][0] = (float4_)0.0f; acc[i][1] = (float4_)0.0f; }
  for (int kk=0; kk<Cx; kk+=32){
    __syncthreads();
    #pragma unroll
    for (int it=0; it<2; ++it){
      int cid = tid + it*256;
      int r = cid >> 2;
      int ko = (cid & 3) << 3;
      *(ui4*)&As[r*LDA + ko] = *(const ui4*)&A[(size_t)(n0+r)*Cx + kk + ko];
    }
    __syncthreads();
    short8 af[4], bf[2];
    #pragma unroll
    for (int i=0;i<4;++i) af[i] = *(const short8*)&As[(wn*64 + i*16 + lm)*LDA + quad*8];
    #pragma unroll
    for (int j=0;j<2;++j) bf[j] = *(const short8*)&Ws[(wo*32 + j*16 + lm)*LDB + kk + quad*8];
    #pragma unroll
    for (int i=0;i<4;++i)
      #pragma unroll
      for (int j=0;j<2;++j)
        acc[i][j] = __builtin_amdgcn_mfma_f32_16x16x32_bf16(af[i], bf[j], acc[i][j], 0, 0, 0);
  }
  const int b = n0 / HWx;
  if (MODE == 1){
    #pragma unroll
    for (int i=0;i<4;++i){
      #pragma unroll
      for (int j=0;j<2;++j){
        int oc = o0 + wo*32 + j*16 + lm;
        float bb = bias[oc];
        #pragma unroll
        for (int r=0;r<4;++r){
          int row = n0 + wn*64 + i*16 + quad*4 + r;
          size_t idx = (size_t)row*Cx + oc;
          float g = sigm(acc[i][j][r] + bb);
          Y[idx] = f2b(0.25f * b2f(Sb[idx]) * g);
        }
      }
    }
  } else {
    float s0=0,s1=0,q0=0,q1=0;
    #pragma unroll
    for (int i=0;i<4;++i){
      #pragma unroll
      for (int j=0;j<2;++j){
        int oc = o0 + wo*32 + j*16 + lm;
        #pragma unroll
        for (int r=0;r<4;++r){
          int row = n0 + wn*64 + i*16 + quad*4 + r;
          float v = acc[i][j][r];
          Y[(size_t)row*Cx + oc] = f2b(v);
          if (j==0){ s0+=v; q0+=v*v; } else { s1+=v; q1+=v*v; }
        }
      }
    }
    s0 += __shfl_xor(s0,16); s0 += __shfl_xor(s0,32);
    q0 += __shfl_xor(q0,16); q0 += __shfl_xor(q0,32);
    s1 += __shfl_xor(s1,16); s1 += __shfl_xor(s1,32);
    q1 += __shfl_xor(q1,16); q1 += __shfl_xor(q1,32);
    if (tid < 128) ((float*)red)[tid] = 0.0f;
    __syncthreads();
    if (lane < 16){
      atomicAdd(&red[wo*2+0][lm][0], s0);
      atomicAdd(&red[wo*2+0][lm][1], q0);
      atomicAdd(&red[wo*2+1][lm][0], s1);
      atomicAdd(&red[wo*2+1][lm][1], q1);
    }
    __syncthreads();
    if (tid < 4){
      float ss=0, qq=0;
      #pragma unroll
      for (int k=0;k<16;++k){ ss += red[tid][k][0]; qq += red[tid][k][1]; }
      int g = (o0 >> 4) + tid;
      atomicAdd(&stats[(b*Gx + g)*2 + 0], ss);
      atomicAdd(&stats[(b*Gx + g)*2 + 1], qq);
    }
  }
}

// ---------------- stats -> mu, rstd ----------------
__global__ void k_finalize(const float* __restrict__ st, float* __restrict__ mr){
  int i = threadIdx.x;   // 256 = 16b x 16g
  float s = st[i*2+0], q = st[i*2+1];
  float mu  = s * (1.0f/GRPN);
  float var = q * (1.0f/GRPN) - mu*mu;
  mr[i*2+0] = mu;
  mr[i*2+1] = rsqrtf(var + 1e-5f);
}

// ---------------- W-direction scans (lr + rl) -> S, fused GN1+SiLU, ZERO-LDS ----------------
// All per-element state lives in GLOBAL memory (bit-identical f2b points vs the verified
// round-2 LDS version): normed input is written to xp and RE-READ in the backward pass
// (24 KB/block, L1-resident); forward-scan partials go directly into S and are RMW-combined
// by the backward pass. No LDS, ~35 VGPR -> occupancy capped only by the 32-wave/CU limit.
// The asm memory barrier stops store-to-load forwarding (which would pin 96 values in
// registers and re-create the round-3/4 spill disaster).
__global__ __launch_bounds__(128) void k_scan_w(const u16* __restrict__ Y1, u16* __restrict__ Xp, u16* __restrict__ S,
    const float* __restrict__ ap, const float* __restrict__ bp, const float* __restrict__ cpr, const float* __restrict__ dp,
    const float* __restrict__ mr, const float* __restrict__ gwv, const float* __restrict__ gbv){
  int blk = blockIdx.x;
  int ch = blk & 1;
  int row = blk >> 1;
  int h = row % Hx, b = row / Hx;
  int t = threadIdx.x;
  int c = ch*128 + t;
  float A0 = sigm(ap[c]),      B0 = bp[c],      C0 = cpr[c],      D0 = dp[c];
  float A1 = sigm(ap[Cx+c]),   B1 = bp[Cx+c],   C1 = cpr[Cx+c],   D1 = dp[Cx+c];
  int g = c >> 4;
  float mu = mr[(b*Gx+g)*2], rs = mr[(b*Gx+g)*2+1];
  float gwc = gwv[c], gbc = gbv[c];
  const u16* base = Y1 + ((size_t)(b*Hx + h)*Wx)*Cx + c;
  u16* xpb = Xp + ((size_t)(b*Hx + h)*Wx)*Cx + c;
  u16* sb  = S  + ((size_t)(b*Hx + h)*Wx)*Cx + c;
  // forward: norm+silu -> xp, forward-scan partial -> S
  float hs = 0.0f;
  #pragma unroll 4
  for (int w=0; w<Wx; ++w){
    float xn = (b2f(base[(size_t)w*Cx]) - mu)*rs*gwc + gbc;
    u16 v = f2b(xn * sigm(xn));
    xpb[(size_t)w*Cx] = v;
    float xv = b2f(v);
    hs = A0*hs + B0*xv;
    sb[(size_t)w*Cx] = f2b(C0*hs + D0*xv);
  }
  asm volatile("" ::: "memory");
  // backward: re-read xp (L1-hot), RMW-combine into S
  hs = 0.0f;
  #pragma unroll 4
  for (int w=Wx-1; w>=0; --w){
    float xv = b2f(xpb[(size_t)w*Cx]);
    hs = A1*hs + B1*xv;
    sb[(size_t)w*Cx] = f2b(C1*hs + D1*xv + b2f(sb[(size_t)w*Cx]));
  }
}

// ---------------- H-direction scans (tb + bt), accumulate into S, ZERO-LDS ----------------
// Forward partials go to the idle xT buffer (free between gemm1 and dwconv); backward pass
// re-reads xp + the partials + S and combines with the exact round-2 rounding.
__global__ __launch_bounds__(128) void k_scan_h(const u16* __restrict__ Xp, u16* __restrict__ S, u16* __restrict__ Av,
    const float* __restrict__ ap, const float* __restrict__ bp, const float* __restrict__ cpr, const float* __restrict__ dp){
  int blk = blockIdx.x;
  int ch = blk & 1;
  int col = blk >> 1;
  int w = col % Wx, b = col / Wx;
  int t = threadIdx.x;
  int c = ch*128 + t;
  float A2 = sigm(ap[2*Cx+c]), B2 = bp[2*Cx+c], C2 = cpr[2*Cx+c], D2 = dp[2*Cx+c];
  float A3 = sigm(ap[3*Cx+c]), B3 = bp[3*Cx+c], C3 = cpr[3*Cx+c], D3 = dp[3*Cx+c];
  const u16* base = Xp + ((size_t)(b*Hx)*Wx + w)*Cx + c;
  u16* av = Av + ((size_t)(b*Hx)*Wx + w)*Cx + c;
  u16* sb = S  + ((size_t)(b*Hx)*Wx + w)*Cx + c;
  float hs = 0.0f;
  #pragma unroll 4
  for (int h=0; h<Hx; ++h){
    float xv = b2f(base[(size_t)h*Wx*Cx]);
    hs = A2*hs + B2*xv;
    av[(size_t)h*Wx*Cx] = f2b(C2*hs + D2*xv);
  }
  asm volatile("" ::: "memory");
  hs = 0.0f;
  #pragma unroll 4
  for (int h=Hx-1; h>=0; --h){
    float xv = b2f(base[(size_t)h*Wx*Cx]);
    hs = A3*hs + B3*xv;
    size_t off = (size_t)h*Wx*Cx;
    sb[off] = f2b(C3*hs + D3*xv + b2f(av[off]) + b2f(sb[off]));
  }
}

// ---------------- depthwise 3x3, channels-last (bf16 act, fp32 weights) ----------------
// Weights in registers; 4 w-outputs x 4 channels per thread; input patch reused across outputs.
__global__ __launch_bounds__(256) void k_dwconv(const u16* __restrict__ F, const float* __restrict__ dwW, u16* __restrict__ O){
  __shared__ float wl[2304];
  int t = threadIdx.x;
  #pragma unroll
  for (int i=0;i<9;++i) wl[t + i*256] = dwW[t + i*256];
  __syncthreads();
  int blk = blockIdx.x;
  int w16 = blk % (Wx/16);
  int h   = (blk/(Wx/16)) % Hx;
  int b   = blk / ((Wx/16)*Hx);
  int cq = (t & 63) << 2;            // channel quad base (lane-major -> 512B coalesced)
  int w0 = (w16 << 4) + ((t >> 6) << 2);  // 4 outputs per thread, wave-uniform
  float wt[36];
  #pragma unroll
  for (int j=0;j<9;++j) *(float4_*)&wt[4*j] = *(const float4_*)&wl[cq*9 + 4*j];
  float acc[4][4];
  #pragma unroll
  for (int ow=0;ow<4;++ow){ acc[ow][0]=0.0f; acc[ow][1]=0.0f; acc[ow][2]=0.0f; acc[ow][3]=0.0f; }
  const u16* Fb = F + ((size_t)(b*Hx)*Wx)*Cx + cq;
  #pragma unroll
  for (int ky=0; ky<3; ++ky){
    int hh = h + ky - 1;
    if (hh < 0 || hh >= Hx) continue;
    #pragma unroll
    for (int j=0; j<6; ++j){            // input cols w0-1 .. w0+4
      int ww = w0 + j - 1;
      if (ww < 0 || ww >= Wx) continue;
      us4 v = *(const us4*)&Fb[((size_t)hh*Wx + ww)*Cx];
      float f0=b2f(v[0]), f1=b2f(v[1]), f2=b2f(v[2]), f3=b2f(v[3]);
      #pragma unroll
      for (int ow = (j-2<0?0:j-2); ow <= (j<3?j:3); ++ow){
        int kidx = ky*3 + (j - ow);
        acc[ow][0] += f0 * wt[0*9 + kidx];
        acc[ow][1] += f1 * wt[1*9 + kidx];
        acc[ow][2] += f2 * wt[2*9 + kidx];
        acc[ow][3] += f3 * wt[3*9 + kidx];
      }
    }
  }
  #pragma unroll
  for (int ow=0; ow<4; ++ow){
    us4 o = { f2b(acc[ow][0]), f2b(acc[ow][1]), f2b(acc[ow][2]), f2b(acc[ow][3]) };
    *(us4*)&O[((size_t)((b*Hx+h)*Wx) + w0 + ow)*Cx + cq] = o;
  }
}

// ---------------- GN-apply + SiLU + transpose back to [b,c,hw] (fp32 out) ----------------
__global__ __launch_bounds__(256) void k_norm_tr(const u16* __restrict__ Y3, float* __restrict__ Out,
    const float* __restrict__ mr, const float* __restrict__ gw, const float* __restrict__ gb){
  __shared__ float tile[32][36];   // [hw][c]
  int blk = blockIdx.x;
  int ct  = blk & 7;
  int hwt = (blk >> 3) % 288;
  int b   = blk / 2304;
  int c0 = ct*32, hw0 = hwt*32;
  int t = threadIdx.x;
  int r  = t >> 3;
  int q4 = (t & 7) << 2;
  us4 v = *(const us4*)&Y3[((size_t)(b*HWx + hw0 + r))*Cx + c0 + q4];
  int g = (c0 + q4) >> 4;
  float mu = mr[(b*Gx+g)*2], rs = mr[(b*Gx+g)*2+1];
  #pragma unroll
  for (int i=0;i<4;++i){
    float xn = (b2f(v[i]) - mu)*rs*gw[c0+q4+i] + gb[c0+q4+i];
    tile[r][q4+i] = xn * sigm(xn);
  }
  __syncthreads();
  float4_ o = { tile[q4+0][r], tile[q4+1][r], tile[q4+2][r], tile[q4+3][r] };
  *(float4_*)&Out[((size_t)(b*Cx + c0 + r))*HWx + hw0 + q4] = o;
}

extern "C" void kernel_launch(void* const* d_in, const int* in_sizes, int n_in,
                              void* d_out, int out_size, void* d_ws, size_t ws_size,
                              hipStream_t stream){
  (void)in_sizes; (void)n_in; (void)out_size; (void)ws_size;
  const float* x    = (const float*)d_in[0];
  const float* in_w = (const float*)d_in[1];
  const float* gn1w = (const float*)d_in[2];
  const float* gn1b = (const float*)d_in[3];
  const float* ap   = (const float*)d_in[4];
  const float* bp   = (const float*)d_in[5];
  const float* cp   = (const float*)d_in[6];
  const float* dp   = (const float*)d_in[7];
  const float* gw   = (const float*)d_in[8];
  const float* gb   = (const float*)d_in[9];
  const float* dww  = (const float*)d_in[10];
  const float* pww  = (const float*)d_in[11];
  const float* gn2w = (const float*)d_in[12];
  const float* gn2b = (const float*)d_in[13];
  float* out = (float*)d_out;
  char* ws = (char*)d_ws;
  const size_t NB = (size_t)NTOK * Cx * 2;   // 75,497,472 bytes per bf16 tensor
  u16* xT = (u16*)(ws);            // transpose out; reused as scan_h partial scratch; reused for dwconv output
  u16* y1 = (u16*)(ws + NB);       // also reused for GEMM3 output
  u16* xp = (u16*)(ws + 2*NB);
  u16* S  = (u16*)(ws + 3*NB);     // scan sum -> fused (in-place)
  float* stats1 = (float*)(ws + 4*NB);
  float* stats2 = stats1 + 512;
  float* mr1    = stats1 + 1024;
  float* mr2    = stats1 + 1536;

  hipMemsetAsync(stats1, 0, 1024*sizeof(float), stream);

  k_transpose<<<36864, 256, 0, stream>>>(x, xT);
  k_gemm<0><<<4608, 256, 0, stream>>>(xT, in_w, y1, stats1, nullptr, nullptr);
  k_finalize<<<1, 256, 0, stream>>>(stats1, mr1);
  k_scan_w<<<Bx*Hx*2, 128, 0, stream>>>(y1, xp, S, ap, bp, cp, dp, mr1, gn1w, gn1b);
  k_scan_h<<<Bx*Wx*2, 128, 0, stream>>>(xp, S, xT, ap, bp, cp, dp);
  k_gemm<1><<<4608, 256, 0, stream>>>(xp, gw, S, nullptr, gb, S);
  k_dwconv<<<Bx*Hx*(Wx/16), 256, 0, stream>>>(S, dww, xT);
  k_gemm<0><<<4608, 256, 0, stream>>>(xT, pww, y1, stats2, nullptr, nullptr);
  k_finalize<<<1, 256, 0, stream>>>(stats2, mr2);
  k_norm_tr<<<36864, 256, 0, stream>>>(y1, out, mr2, gn2w, gn2b);
}